// Round 5
// baseline (467.132 us; speedup 1.0000x reference)
//
#include <hip/hip_runtime.h>
#include <hip/hip_bf16.h>

#define NN   100000
#define DD   128
#define ZZ   128
#define TT   1024
#define KK   256
#define HIDD 512

typedef __attribute__((ext_vector_type(8))) short  short8;   // 8 bf16 (MFMA A/B frag)
typedef __attribute__((ext_vector_type(4))) float  f32x4;    // MFMA C/D frag

__device__ inline unsigned short f2bf(float f) {  // RTNE fp32 -> bf16
    union { float f; unsigned int u; } x; x.f = f;
    unsigned int r = x.u + 0x7fffu + ((x.u >> 16) & 1u);
    return (unsigned short)(r >> 16);
}
__device__ inline void load_lds16(const void* g, void* l) {
    __builtin_amdgcn_global_load_lds((const __attribute__((address_space(1))) unsigned int*)g,
                                     (__attribute__((address_space(3))) unsigned int*)l, 16, 0, 0);
}

// ---------------- Kernel 1: zpe = z + pe@W_pe (bf16), ctx cast to bf16 — 8 elems/thread ----------------
__global__ __launch_bounds__(256) void prep_tables(
    const float* __restrict__ pe, const float* __restrict__ ctx,
    const float* __restrict__ z, const float* __restrict__ wpe,
    unsigned short* __restrict__ ctx_bf, unsigned short* __restrict__ zpe_bf) {
    int g = blockIdx.x * 256 + threadIdx.x;      // one thread per 8 elements
    if (g >= NN * 16) return;
    int n = g >> 4, j8 = (g & 15) << 3;
    float p0 = pe[n * 4 + 0], p1 = pe[n * 4 + 1], p2 = pe[n * 4 + 2], p3 = pe[n * 4 + 3];
    float4 c0 = *(const float4*)(ctx + (size_t)n * 128 + j8);
    float4 c1 = *(const float4*)(ctx + (size_t)n * 128 + j8 + 4);
    float4 z0 = *(const float4*)(z + j8);
    float4 z1 = *(const float4*)(z + j8 + 4);
    float4 wa0 = *(const float4*)(wpe + 0 * ZZ + j8), wa1 = *(const float4*)(wpe + 0 * ZZ + j8 + 4);
    float4 wb0 = *(const float4*)(wpe + 1 * ZZ + j8), wb1 = *(const float4*)(wpe + 1 * ZZ + j8 + 4);
    float4 wc0 = *(const float4*)(wpe + 2 * ZZ + j8), wc1 = *(const float4*)(wpe + 2 * ZZ + j8 + 4);
    float4 wd0 = *(const float4*)(wpe + 3 * ZZ + j8), wd1 = *(const float4*)(wpe + 3 * ZZ + j8 + 4);
    float zp[8], cv[8];
    zp[0] = z0.x + p0 * wa0.x + p1 * wb0.x + p2 * wc0.x + p3 * wd0.x;
    zp[1] = z0.y + p0 * wa0.y + p1 * wb0.y + p2 * wc0.y + p3 * wd0.y;
    zp[2] = z0.z + p0 * wa0.z + p1 * wb0.z + p2 * wc0.z + p3 * wd0.z;
    zp[3] = z0.w + p0 * wa0.w + p1 * wb0.w + p2 * wc0.w + p3 * wd0.w;
    zp[4] = z1.x + p0 * wa1.x + p1 * wb1.x + p2 * wc1.x + p3 * wd1.x;
    zp[5] = z1.y + p0 * wa1.y + p1 * wb1.y + p2 * wc1.y + p3 * wd1.y;
    zp[6] = z1.z + p0 * wa1.z + p1 * wb1.z + p2 * wc1.z + p3 * wd1.z;
    zp[7] = z1.w + p0 * wa1.w + p1 * wb1.w + p2 * wc1.w + p3 * wd1.w;
    cv[0] = c0.x; cv[1] = c0.y; cv[2] = c0.z; cv[3] = c0.w;
    cv[4] = c1.x; cv[5] = c1.y; cv[6] = c1.z; cv[7] = c1.w;
    short8 sz, sc;
#pragma unroll
    for (int i = 0; i < 8; ++i) { sz[i] = (short)f2bf(zp[i]); sc[i] = (short)f2bf(cv[i]); }
    *(short8*)(zpe_bf + (size_t)g * 8) = sz;
    *(short8*)(ctx_bf + (size_t)g * 8) = sc;
}

// ---------------- Kernel 2: pack W1/W2 into MFMA frag order + ct = b1 + z_tgt@W1c ----------------
// Frag tile (16 out x 32 k): lane l elem e -> k_local = (l>>4)*8 + e, out = l&15.
// W1 tiles use a permuted out-mapping so GEMM1's C-rows concatenate into a standard
// 16x16x32 A-frag: tile pair (2g,2g+1) covers hcols g*32 + {hi*8 + nt*4 + r}.
// Blocks 0..767: packing. Blocks 768..895: ct for 8 targets each.
__global__ __launch_bounds__(256) void pack_ct(
    const float* __restrict__ W1, const float* __restrict__ W2,
    const float* __restrict__ pe, const float* __restrict__ z, const float* __restrict__ wpe,
    const int* __restrict__ target_nodes, const float* __restrict__ b1,
    unsigned short* __restrict__ w1p, unsigned short* __restrict__ w2p, float* __restrict__ ct_g) {
    __shared__ float zp[8][128];
    int tid = threadIdx.x;
    if (blockIdx.x < 768) {
        int g = blockIdx.x * 256 + tid;
        if (g < 256 * HIDD) {                         // W1 rows 0..255 (ctx|zpe parts)
            int e = g & 7, l = (g >> 3) & 63, tile = g >> 9;
            int ntg = tile & 7, rem = tile >> 3;      // rem = hc*8 + kc
            int kc = rem & 7, hc = rem >> 3;
            int k = kc * 32 + (l >> 4) * 8 + e;
            int o = l & 15;
            int n = hc * 128 + (ntg >> 1) * 32 + ((o >> 2) << 3) + (o & 3) + ((ntg & 1) << 2);
            w1p[g] = f2bf(W1[(size_t)k * HIDD + n]);
        } else {
            int q = g - 256 * HIDD;
            int e = q & 7, l = (q >> 3) & 63, tile = q >> 9;
            int ntg = tile & 7, kcg = tile >> 3;
            int k = kcg * 32 + (l >> 4) * 8 + e;
            int n = ntg * 16 + (l & 15);
            w2p[q] = f2bf(W2[(size_t)k * DD + n]);
        }
        return;
    }
    int b = blockIdx.x - 768;                         // 0..127, 8 targets each
#pragma unroll
    for (int q = 0; q < 4; ++q) {
        int idx = q * 256 + tid;                      // 0..1023
        int t8 = idx >> 7, zz = idx & 127;
        int tgt = target_nodes[b * 8 + t8];
        zp[t8][zz] = z[zz] + pe[tgt * 4 + 0] * wpe[zz] + pe[tgt * 4 + 1] * wpe[128 + zz]
                           + pe[tgt * 4 + 2] * wpe[256 + zz] + pe[tgt * 4 + 3] * wpe[384 + zz];
    }
    __syncthreads();
    int j0 = tid, j1 = tid + 256;
    float a0[8], a1[8];
    float bb0 = b1[j0], bb1 = b1[j1];
#pragma unroll
    for (int t8 = 0; t8 < 8; ++t8) { a0[t8] = bb0; a1[t8] = bb1; }
#pragma unroll 8
    for (int zz = 0; zz < 128; ++zz) {
        float w0 = W1[(size_t)(256 + zz) * HIDD + j0];
        float w1 = W1[(size_t)(256 + zz) * HIDD + j1];
#pragma unroll
        for (int t8 = 0; t8 < 8; ++t8) { a0[t8] += zp[t8][zz] * w0; a1[t8] += zp[t8][zz] * w1; }
    }
#pragma unroll
    for (int t8 = 0; t8 < 8; ++t8) {
        ct_g[(size_t)(b * 8 + t8) * HIDD + j0] = a0[t8];
        ct_g[(size_t)(b * 8 + t8) * HIDD + j1] = a1[t8];
    }
}

// ---------------- Kernel 3: fused gather + MLP + masked-MSE ----------------
// Block = (target t, 64-row K-tile). 4 waves; wave w owns hcols [w*32 .. w*32+31] of every
// hc chunk (k-split). GEMM1 (swapped mfma) + perm-packed W1 leaves each lane's two relu'd
// acc tiles forming a standard 16x16x32 A-frag -> GEMM2 runs straight from registers.
// NO hT, NO barriers in the hc loop. Wave partials merged via two parallel psum LDS bufs.
__global__ __launch_bounds__(256, 2) void mp_jepa_main(
    const unsigned short* __restrict__ ctx_bf,
    const unsigned short* __restrict__ zpe_bf,
    const unsigned short* __restrict__ w1p,
    const unsigned short* __restrict__ w2p,
    const float* __restrict__ ct_g,
    const float* __restrict__ target_embedding,
    const int* __restrict__ sub_nodes,
    const int* __restrict__ sub_counts,
    const int* __restrict__ target_nodes,
    const float* __restrict__ b2,
    float* __restrict__ out) {
    const int bid = blockIdx.x;
    const int t = bid >> 2, kt = bid & 3;
    const int k0 = kt * 64;
    int cnt = sub_counts[t]; if (cnt < 1) cnt = 1;
    if (k0 >= cnt) return;           // uniform early-exit before any barrier
    const int tgt = target_nodes[t];

    __shared__ __align__(16) char smem[32768];       // ctxT(16K)+zpeT(16K); aliased psumA(32K)
    __shared__ __align__(16) float psumB[8192];      // 32K
    __shared__ __align__(16) float cts[HIDD];
    __shared__ float tgte[DD];
    __shared__ float b2s[DD];
    __shared__ float red[4];
    unsigned short* ctxT = (unsigned short*)smem;
    unsigned short* zpeT = (unsigned short*)(smem + 16384);
    float* psumA = (float*)smem;

    const int tid = threadIdx.x;
    const int w = tid >> 6, l = tid & 63;
    const int lo = l & 15, hi = l >> 4;

    // Async gather: linear LDS dest (base + lane*16), inverse-swizzled global source.
    {
        const char* cc = (const char*)ctx_bf;
        const char* zc = (const char*)zpe_bf;
        const int base = t * KK + k0;
#pragma unroll
        for (int it = 0; it < 4; ++it) {
            int rgrp = it * 16 + (w << 2);        // wave-uniform row-group base (4 rows)
            int row  = rgrp + hi;
            int node = sub_nodes[base + row];
            int soff = (lo << 4) ^ ((row & 7) << 4);
            load_lds16(cc + (size_t)node * 256 + soff, (char*)ctxT + rgrp * 256);
            load_lds16(zc + (size_t)node * 256 + soff, (char*)zpeT + rgrp * 256);
        }
    }
    // params load overlaps the in-flight gather
    if (tid < 128) {
        tgte[tid] = target_embedding[(size_t)tgt * 128 + tid];
        b2s[tid]  = b2[tid];
    }
    cts[tid]       = ct_g[(size_t)t * HIDD + tid];
    cts[tid + 256] = ct_g[(size_t)t * HIDD + tid + 256];
    __syncthreads();

    const short8* w1v = (const short8*)w1p;
    const short8* w2v = (const short8*)w2p;

    f32x4 accP[4][8];                                // pred partial: rows rg*16+hi*4+r, col nt8*16+lo
#pragma unroll
    for (int rg = 0; rg < 4; ++rg)
#pragma unroll
        for (int nt8 = 0; nt8 < 8; ++nt8) accP[rg][nt8] = (f32x4){0.f, 0.f, 0.f, 0.f};

#pragma unroll
    for (int hc = 0; hc < 4; ++hc) {
        // ---- GEMM1 (swapped): acc1[rg][nt] row r -> hcol hc*128 + w*32 + hi*8 + nt*4 + r
        f32x4 acc1[4][2];
#pragma unroll
        for (int nt = 0; nt < 2; ++nt) {
            f32x4 cv = *(const f32x4*)&cts[(hc << 7) + (w << 5) + (hi << 3) + (nt << 2)];
#pragma unroll
            for (int rg = 0; rg < 4; ++rg) acc1[rg][nt] = cv;
        }
#pragma unroll
        for (int kc = 0; kc < 8; ++kc) {
            short8 bf0 = w1v[((((hc << 3) + kc) << 3) + (w << 1) + 0) * 64 + l];
            short8 bf1 = w1v[((((hc << 3) + kc) << 3) + (w << 1) + 1) * 64 + l];
            const unsigned short* src = (kc < 4) ? ctxT : zpeT;
            int cb = ((kc & 3) << 6) + (hi << 4);
            short8 a[4];
#pragma unroll
            for (int rg = 0; rg < 4; ++rg) {
                int row = (rg << 4) + lo;
                a[rg] = *(const short8*)(src + ((row * 256 + (cb ^ ((row & 7) << 4))) >> 1));
            }
#pragma unroll
            for (int rg = 0; rg < 4; ++rg) {
                acc1[rg][0] = __builtin_amdgcn_mfma_f32_16x16x32_bf16(bf0, a[rg], acc1[rg][0], 0, 0, 0);
                acc1[rg][1] = __builtin_amdgcn_mfma_f32_16x16x32_bf16(bf1, a[rg], acc1[rg][1], 0, 0, 0);
            }
        }
        // ---- relu + pack: lane's 8 values = standard A-frag (k = hi*8+e) for k32 tile hc*4+w
        short8 a32[4];
#pragma unroll
        for (int rg = 0; rg < 4; ++rg) {
#pragma unroll
            for (int e = 0; e < 4; ++e) {
                float v0 = acc1[rg][0][e]; v0 = v0 > 0.f ? v0 : 0.f;
                float v1 = acc1[rg][1][e]; v1 = v1 > 0.f ? v1 : 0.f;
                a32[rg][e]     = (short)f2bf(v0);
                a32[rg][e + 4] = (short)f2bf(v1);
            }
        }
        // ---- GEMM2 partial from registers: accP += h[:, k-slice] @ W2[k-slice, :]
        int kcg = (hc << 2) + w;
#pragma unroll
        for (int nt8 = 0; nt8 < 8; ++nt8) {
            short8 wb = w2v[((kcg << 3) + nt8) * 64 + l];
#pragma unroll
            for (int rg = 0; rg < 4; ++rg)
                accP[rg][nt8] = __builtin_amdgcn_mfma_f32_16x16x32_bf16(a32[rg], wb, accP[rg][nt8], 0, 0, 0);
        }
    }

    // ---- merge wave k-partials: w0/w1 write psumA/psumB, w2/w3 add into them
    __syncthreads();                                  // ctxT/zpeT dead; all A-reads done
#pragma unroll
    for (int rg = 0; rg < 4; ++rg)
#pragma unroll
        for (int nt8 = 0; nt8 < 8; ++nt8) {
            int col = (nt8 << 4) + lo;
            int word = ((col << 6) + (rg << 4) + (hi << 2)) ^ ((col & 7) << 2);
            if (w == 0) *(f32x4*)(psumA + word) = accP[rg][nt8];
            if (w == 1) *(f32x4*)(psumB + word) = accP[rg][nt8];
        }
    __syncthreads();
#pragma unroll
    for (int rg = 0; rg < 4; ++rg)
#pragma unroll
        for (int nt8 = 0; nt8 < 8; ++nt8) {
            int col = (nt8 << 4) + lo;
            int word = ((col << 6) + (rg << 4) + (hi << 2)) ^ ((col & 7) << 2);
            if (w == 2) { f32x4 v = *(f32x4*)(psumA + word); v += accP[rg][nt8]; *(f32x4*)(psumA + word) = v; }
            if (w == 3) { f32x4 v = *(f32x4*)(psumB + word); v += accP[rg][nt8]; *(f32x4*)(psumB + word) = v; }
        }
    __syncthreads();

    // ---- masked squared error + reduction (each thread: 8 x f32x4 quads)
    float s = 0.f;
#pragma unroll
    for (int rq = 0; rq < 8; ++rq) {
        int base = (rq << 10) + (tid << 2);           // unswizzled word = col*64 + row
        int col = base >> 6;
        int row0 = base & 63;
        int word = base ^ ((col & 7) << 2);
        f32x4 va = *(const f32x4*)(psumA + word);
        f32x4 vb = *(const f32x4*)(psumB + word);
        float bb = b2s[col] - tgte[col];
#pragma unroll
        for (int r = 0; r < 4; ++r) {
            float d = va[r] + vb[r] + bb;
            if (k0 + row0 + r < cnt) s += d * d;
        }
    }
#pragma unroll
    for (int off = 32; off > 0; off >>= 1) s += __shfl_xor(s, off, 64);
    if (l == 0) red[w] = s;
    __syncthreads();
    if (tid == 0) {
        float tot = (red[0] + red[1] + red[2] + red[3]) / ((float)cnt * 128.0f);
        atomicAdd(out, tot);
    }
}

extern "C" void kernel_launch(void* const* d_in, const int* in_sizes, int n_in,
                              void* d_out, int out_size, void* d_ws, size_t ws_size,
                              hipStream_t stream) {
    const float* pe           = (const float*)d_in[0];
    const float* ctx          = (const float*)d_in[1];
    const float* tgt_emb      = (const float*)d_in[2];
    const int*   sub_nodes    = (const int*)d_in[3];
    const int*   sub_counts   = (const int*)d_in[4];
    const int*   target_nodes = (const int*)d_in[5];
    const float* z            = (const float*)d_in[6];
    const float* wpe          = (const float*)d_in[7];
    const float* W1           = (const float*)d_in[8];
    const float* b1           = (const float*)d_in[9];
    const float* W2           = (const float*)d_in[10];
    const float* b2           = (const float*)d_in[11];
    float* out = (float*)d_out;

    char* ws = (char*)d_ws;
    unsigned short* ctx_bf = (unsigned short*)ws;                              // 25.6 MB
    unsigned short* zpe_bf = (unsigned short*)(ws + 25600000);                 // 25.6 MB
    unsigned short* w1p    = (unsigned short*)(ws + 51200000);                 // 256 KB
    unsigned short* w2p    = (unsigned short*)(ws + 51200000 + 262144);        // 128 KB
    float*          ct_g   = (float*)(ws + 51200000 + 262144 + 131072);        // 2 MB

    hipMemsetAsync(d_out, 0, sizeof(float), stream);
    prep_tables<<<(NN * 16 + 255) / 256, 256, 0, stream>>>(pe, ctx, z, wpe, ctx_bf, zpe_bf);
    pack_ct<<<896, 256, 0, stream>>>(W1, W2, pe, z, wpe, target_nodes, b1, w1p, w2p, ct_g);
    mp_jepa_main<<<TT * 4, 256, 0, stream>>>(ctx_bf, zpe_bf, w1p, w2p, ct_g, tgt_emb,
                                             sub_nodes, sub_counts, target_nodes, b2, out);
}

// Round 7
// 248.906 us; speedup vs baseline: 1.8767x; 1.8767x over previous
//
#include <hip/hip_runtime.h>
#include <hip/hip_bf16.h>

#define NN   100000
#define DD   128
#define ZZ   128
#define TT   1024
#define KK   256
#define HIDD 512

typedef __attribute__((ext_vector_type(8))) short  short8;   // 8 bf16 (MFMA A/B frag)
typedef __attribute__((ext_vector_type(4))) float  f32x4;    // MFMA C/D frag

__device__ inline unsigned short f2bf(float f) {  // RTNE fp32 -> bf16
    union { float f; unsigned int u; } x; x.f = f;
    unsigned int r = x.u + 0x7fffu + ((x.u >> 16) & 1u);
    return (unsigned short)(r >> 16);
}
__device__ inline void load_lds16(const void* g, void* l) {
    __builtin_amdgcn_global_load_lds((const __attribute__((address_space(1))) unsigned int*)g,
                                     (__attribute__((address_space(3))) unsigned int*)l, 16, 0, 0);
}

// ---------------- Kernel 1: zpe = z + pe@W_pe (bf16), ctx cast to bf16 — 8 elems/thread ----------------
__global__ __launch_bounds__(256) void prep_tables(
    const float* __restrict__ pe, const float* __restrict__ ctx,
    const float* __restrict__ z, const float* __restrict__ wpe,
    unsigned short* __restrict__ ctx_bf, unsigned short* __restrict__ zpe_bf) {
    int g = blockIdx.x * 256 + threadIdx.x;      // one thread per 8 elements
    if (g >= NN * 16) return;
    int n = g >> 4, j8 = (g & 15) << 3;
    float p0 = pe[n * 4 + 0], p1 = pe[n * 4 + 1], p2 = pe[n * 4 + 2], p3 = pe[n * 4 + 3];
    float4 c0 = *(const float4*)(ctx + (size_t)n * 128 + j8);
    float4 c1 = *(const float4*)(ctx + (size_t)n * 128 + j8 + 4);
    float4 z0 = *(const float4*)(z + j8);
    float4 z1 = *(const float4*)(z + j8 + 4);
    float4 wa0 = *(const float4*)(wpe + 0 * ZZ + j8), wa1 = *(const float4*)(wpe + 0 * ZZ + j8 + 4);
    float4 wb0 = *(const float4*)(wpe + 1 * ZZ + j8), wb1 = *(const float4*)(wpe + 1 * ZZ + j8 + 4);
    float4 wc0 = *(const float4*)(wpe + 2 * ZZ + j8), wc1 = *(const float4*)(wpe + 2 * ZZ + j8 + 4);
    float4 wd0 = *(const float4*)(wpe + 3 * ZZ + j8), wd1 = *(const float4*)(wpe + 3 * ZZ + j8 + 4);
    float zp[8], cv[8];
    zp[0] = z0.x + p0 * wa0.x + p1 * wb0.x + p2 * wc0.x + p3 * wd0.x;
    zp[1] = z0.y + p0 * wa0.y + p1 * wb0.y + p2 * wc0.y + p3 * wd0.y;
    zp[2] = z0.z + p0 * wa0.z + p1 * wb0.z + p2 * wc0.z + p3 * wd0.z;
    zp[3] = z0.w + p0 * wa0.w + p1 * wb0.w + p2 * wc0.w + p3 * wd0.w;
    zp[4] = z1.x + p0 * wa1.x + p1 * wb1.x + p2 * wc1.x + p3 * wd1.x;
    zp[5] = z1.y + p0 * wa1.y + p1 * wb1.y + p2 * wc1.y + p3 * wd1.y;
    zp[6] = z1.z + p0 * wa1.z + p1 * wb1.z + p2 * wc1.z + p3 * wd1.z;
    zp[7] = z1.w + p0 * wa1.w + p1 * wb1.w + p2 * wc1.w + p3 * wd1.w;
    cv[0] = c0.x; cv[1] = c0.y; cv[2] = c0.z; cv[3] = c0.w;
    cv[4] = c1.x; cv[5] = c1.y; cv[6] = c1.z; cv[7] = c1.w;
    short8 sz, sc;
#pragma unroll
    for (int i = 0; i < 8; ++i) { sz[i] = (short)f2bf(zp[i]); sc[i] = (short)f2bf(cv[i]); }
    *(short8*)(zpe_bf + (size_t)g * 8) = sz;
    *(short8*)(ctx_bf + (size_t)g * 8) = sc;
}

// ---------------- Kernel 2: pack W1(k<256)/W2 into MFMA frag order + ct = b1 + z_tgt@W1c ----------------
// Frag tile (16 out x 32 k): lane l elem e -> k_local = (l>>4)*8 + e, out = l&15. (standard mapping)
// Blocks 0..767: packing. Blocks 768..895: ct for 8 targets each.
__global__ __launch_bounds__(256) void pack_ct(
    const float* __restrict__ W1, const float* __restrict__ W2,
    const float* __restrict__ pe, const float* __restrict__ z, const float* __restrict__ wpe,
    const int* __restrict__ target_nodes, const float* __restrict__ b1,
    unsigned short* __restrict__ w1p, unsigned short* __restrict__ w2p, float* __restrict__ ct_g) {
    __shared__ float zp[8][128];
    int tid = threadIdx.x;
    if (blockIdx.x < 768) {
        int g = blockIdx.x * 256 + tid;
        if (g < 256 * HIDD) {                         // W1 rows 0..255 (ctx|zpe parts)
            int e = g & 7, l = (g >> 3) & 63, tile = g >> 9;
            int ntg = tile & 7, rem = tile >> 3;      // rem = hc*8 + kc
            int kc = rem & 7, hc = rem >> 3;
            int k = kc * 32 + (l >> 4) * 8 + e;
            int n = hc * 128 + ntg * 16 + (l & 15);
            w1p[g] = f2bf(W1[(size_t)k * HIDD + n]);
        } else {
            int q = g - 256 * HIDD;
            int e = q & 7, l = (q >> 3) & 63, tile = q >> 9;
            int ntg = tile & 7, kcg = tile >> 3;
            int k = kcg * 32 + (l >> 4) * 8 + e;
            int n = ntg * 16 + (l & 15);
            w2p[q] = f2bf(W2[(size_t)k * DD + n]);
        }
        return;
    }
    int b = blockIdx.x - 768;                         // 0..127, 8 targets each
#pragma unroll
    for (int q = 0; q < 4; ++q) {
        int idx = q * 256 + tid;                      // 0..1023
        int t8 = idx >> 7, zz = idx & 127;
        int tgt = target_nodes[b * 8 + t8];
        zp[t8][zz] = z[zz] + pe[tgt * 4 + 0] * wpe[zz] + pe[tgt * 4 + 1] * wpe[128 + zz]
                           + pe[tgt * 4 + 2] * wpe[256 + zz] + pe[tgt * 4 + 3] * wpe[384 + zz];
    }
    __syncthreads();
    int j0 = tid, j1 = tid + 256;
    float a0[8], a1[8];
    float bb0 = b1[j0], bb1 = b1[j1];
#pragma unroll
    for (int t8 = 0; t8 < 8; ++t8) { a0[t8] = bb0; a1[t8] = bb1; }
#pragma unroll 8
    for (int zz = 0; zz < 128; ++zz) {
        float w0 = W1[(size_t)(256 + zz) * HIDD + j0];
        float w1 = W1[(size_t)(256 + zz) * HIDD + j1];
#pragma unroll
        for (int t8 = 0; t8 < 8; ++t8) { a0[t8] += zp[t8][zz] * w0; a1[t8] += zp[t8][zz] * w1; }
    }
#pragma unroll
    for (int t8 = 0; t8 < 8; ++t8) {
        ct_g[(size_t)(b * 8 + t8) * HIDD + j0] = a0[t8];
        ct_g[(size_t)(b * 8 + t8) * HIDD + j1] = a1[t8];
    }
}

// ---------------- Kernel 3: fused gather + MLP + masked-MSE ----------------
// Block = (target t, 64-row K-tile), 8 waves / 512 threads. Wave w: wm=w&1 (row half,
// 32 rows), wn=w>>1 (16-col tile pair). Per-wave work: 2rg x 2nt in both GEMMs (a-frag
// reuse x2). GEMM1 swapped (mfma(W1,agg)) -> lane holds 4 consecutive hcols of one
// agg-row -> conflict-free b64 hT writes with ^((row&7)<<4); GEMM2 b128 reads use the
// same swizzle (both are slot-permutations per 8-lane group).
__global__ __launch_bounds__(512) void mp_jepa_main(
    const unsigned short* __restrict__ ctx_bf,
    const unsigned short* __restrict__ zpe_bf,
    const unsigned short* __restrict__ w1p,
    const unsigned short* __restrict__ w2p,
    const float* __restrict__ ct_g,
    const float* __restrict__ target_embedding,
    const int* __restrict__ sub_nodes,
    const int* __restrict__ sub_counts,
    const int* __restrict__ target_nodes,
    const float* __restrict__ b2,
    float* __restrict__ out) {
    const int bid = blockIdx.x;
    const int kt = bid >> 10, t = bid & 1023;         // kt-major: uniform load mix per CU
    const int k0 = kt * 64;
    int cnt = sub_counts[t]; if (cnt < 1) cnt = 1;
    if (k0 >= cnt) return;           // uniform early-exit before any barrier
    const int tgt = target_nodes[t];

    __shared__ __align__(16) unsigned short ctxT[64 * 128];  // 16 KB, swizzled ^((row&7)<<4)
    __shared__ __align__(16) unsigned short zpeT[64 * 128];  // 16 KB, swizzled
    __shared__ __align__(16) unsigned short hT[64 * 128];    // 16 KB, swizzled
    __shared__ float cts[HIDD];
    __shared__ float tgte[DD];
    __shared__ float b2s[DD];
    __shared__ float red[8];

    const int tid = threadIdx.x;
    const int w = tid >> 6, l = tid & 63;
    const int wm = w & 1, wn = w >> 1;                // row half / col-tile pair
    const int lo = l & 15, hi = l >> 4;

    // Async gather: linear LDS dest (base + lane*16), inverse-swizzled global source.
    {
        const char* cc = (const char*)ctx_bf;
        const char* zc = (const char*)zpe_bf;
        const int base = t * KK + k0;
#pragma unroll
        for (int it = 0; it < 2; ++it) {
            int rgrp = it * 32 + (w << 2);        // wave-uniform row-group base (4 rows)
            int row  = rgrp + hi;
            int node = sub_nodes[base + row];
            int soff = (lo << 4) ^ ((row & 7) << 4);
            load_lds16(cc + (size_t)node * 256 + soff, (char*)ctxT + rgrp * 256);
            load_lds16(zc + (size_t)node * 256 + soff, (char*)zpeT + rgrp * 256);
        }
    }
    // params load overlaps the in-flight gather
    if (tid < 128) {
        tgte[tid] = target_embedding[(size_t)tgt * 128 + tid];
        b2s[tid]  = b2[tid];
    }
    cts[tid] = ct_g[(size_t)t * HIDD + tid];
    __syncthreads();

    const short8* w1v = (const short8*)w1p;
    const short8* w2v = (const short8*)w2p;

    f32x4 accP[2][2];                                 // [rg][nt]: rows wm*32+rg*16, cols (wn*2+nt)*16
#pragma unroll
    for (int rg = 0; rg < 2; ++rg)
#pragma unroll
        for (int nt = 0; nt < 2; ++nt) accP[rg][nt] = (f32x4){0.f, 0.f, 0.f, 0.f};

    for (int hc = 0; hc < 4; ++hc) {
        // ---- GEMM1 (swapped): acc1[rg][nt]: hcols (wn*2+nt)*16 + hi*4 + r, agg-rows wm*32+rg*16+lo
        f32x4 acc1[2][2];
#pragma unroll
        for (int nt = 0; nt < 2; ++nt) {
            f32x4 cv = *(const f32x4*)&cts[(hc << 7) + (((wn << 1) + nt) << 4) + (hi << 2)];
            acc1[0][nt] = cv;
            acc1[1][nt] = cv;
        }
#pragma unroll
        for (int kc = 0; kc < 8; ++kc) {
            short8 bf0 = w1v[((((hc << 3) + kc) << 3) + (wn << 1) + 0) * 64 + l];
            short8 bf1 = w1v[((((hc << 3) + kc) << 3) + (wn << 1) + 1) * 64 + l];
            const unsigned short* src = (kc < 4) ? ctxT : zpeT;
            int cb = ((kc & 3) << 6) + (hi << 4);
            short8 a[2];
#pragma unroll
            for (int rg = 0; rg < 2; ++rg) {
                int row = (wm << 5) + (rg << 4) + lo;
                a[rg] = *(const short8*)(src + ((row * 256 + (cb ^ ((row & 7) << 4))) >> 1));
            }
#pragma unroll
            for (int rg = 0; rg < 2; ++rg) {
                acc1[rg][0] = __builtin_amdgcn_mfma_f32_16x16x32_bf16(bf0, a[rg], acc1[rg][0], 0, 0, 0);
                acc1[rg][1] = __builtin_amdgcn_mfma_f32_16x16x32_bf16(bf1, a[rg], acc1[rg][1], 0, 0, 0);
            }
        }

        __syncthreads();  // prior GEMM2 finished reading hT
        // relu -> bf16 -> hT: each lane writes 4 consecutive h-cols of one agg-row (b64)
#pragma unroll
        for (int nt = 0; nt < 2; ++nt) {
            int cbase = (((wn << 1) + nt) << 5) + (hi << 3);   // byte offset of 4 h-cols
#pragma unroll
            for (int rg = 0; rg < 2; ++rg) {
                int row = (wm << 5) + (rg << 4) + lo;
                f32x4 v = acc1[rg][nt];
                float v0 = v[0] > 0.f ? v[0] : 0.f;
                float v1 = v[1] > 0.f ? v[1] : 0.f;
                float v2 = v[2] > 0.f ? v[2] : 0.f;
                float v3 = v[3] > 0.f ? v[3] : 0.f;
                uint2 p;
                p.x = (unsigned int)f2bf(v0) | ((unsigned int)f2bf(v1) << 16);
                p.y = (unsigned int)f2bf(v2) | ((unsigned int)f2bf(v3) << 16);
                *(uint2*)((char*)hT + row * 256 + (cbase ^ ((row & 7) << 4))) = p;
            }
        }
        __syncthreads();

        // ---- GEMM2 partial: pred += relu_h[64,128] @ W2[hc*128.., 128]
#pragma unroll
        for (int kc2 = 0; kc2 < 4; ++kc2) {
            short8 bg0 = w2v[((((hc << 2) + kc2) << 3) + (wn << 1) + 0) * 64 + l];
            short8 bg1 = w2v[((((hc << 2) + kc2) << 3) + (wn << 1) + 1) * 64 + l];
            int cb = (kc2 << 6) + (hi << 4);
#pragma unroll
            for (int rg = 0; rg < 2; ++rg) {
                int row = (wm << 5) + (rg << 4) + lo;
                short8 a = *(const short8*)(hT + ((row * 256 + (cb ^ ((row & 7) << 4))) >> 1));
                accP[rg][0] = __builtin_amdgcn_mfma_f32_16x16x32_bf16(a, bg0, accP[rg][0], 0, 0, 0);
                accP[rg][1] = __builtin_amdgcn_mfma_f32_16x16x32_bf16(a, bg1, accP[rg][1], 0, 0, 0);
            }
        }
    }

    // ---- masked squared error + reduction
    float s = 0.f;
#pragma unroll
    for (int nt = 0; nt < 2; ++nt) {
        int col = (((wn << 1) + nt) << 4) + lo;
        float bb = b2s[col] - tgte[col];
#pragma unroll
        for (int rg = 0; rg < 2; ++rg) {
#pragma unroll
            for (int r = 0; r < 4; ++r) {
                int row = (wm << 5) + (rg << 4) + (hi << 2) + r;  // C/D: col=lane&15, row=(lane>>4)*4+r
                float d = accP[rg][nt][r] + bb;
                if (k0 + row < cnt) s += d * d;
            }
        }
    }
#pragma unroll
    for (int off = 32; off > 0; off >>= 1) s += __shfl_xor(s, off, 64);
    if (l == 0) red[w] = s;
    __syncthreads();
    if (tid == 0) {
        float tot = (red[0] + red[1] + red[2] + red[3] + red[4] + red[5] + red[6] + red[7])
                    / ((float)cnt * 128.0f);
        atomicAdd(out, tot);
    }
}

extern "C" void kernel_launch(void* const* d_in, const int* in_sizes, int n_in,
                              void* d_out, int out_size, void* d_ws, size_t ws_size,
                              hipStream_t stream) {
    const float* pe           = (const float*)d_in[0];
    const float* ctx          = (const float*)d_in[1];
    const float* tgt_emb      = (const float*)d_in[2];
    const int*   sub_nodes    = (const int*)d_in[3];
    const int*   sub_counts   = (const int*)d_in[4];
    const int*   target_nodes = (const int*)d_in[5];
    const float* z            = (const float*)d_in[6];
    const float* wpe          = (const float*)d_in[7];
    const float* W1           = (const float*)d_in[8];
    const float* b1           = (const float*)d_in[9];
    const float* W2           = (const float*)d_in[10];
    const float* b2           = (const float*)d_in[11];
    float* out = (float*)d_out;

    char* ws = (char*)d_ws;
    unsigned short* ctx_bf = (unsigned short*)ws;                              // 25.6 MB
    unsigned short* zpe_bf = (unsigned short*)(ws + 25600000);                 // 25.6 MB
    unsigned short* w1p    = (unsigned short*)(ws + 51200000);                 // 256 KB
    unsigned short* w2p    = (unsigned short*)(ws + 51200000 + 262144);        // 128 KB
    float*          ct_g   = (float*)(ws + 51200000 + 262144 + 131072);        // 2 MB

    hipMemsetAsync(d_out, 0, sizeof(float), stream);
    prep_tables<<<(NN * 16 + 255) / 256, 256, 0, stream>>>(pe, ctx, z, wpe, ctx_bf, zpe_bf);
    pack_ct<<<896, 256, 0, stream>>>(W1, W2, pe, z, wpe, target_nodes, b1, w1p, w2p, ct_g);
    mp_jepa_main<<<TT * 4, 512, 0, stream>>>(ctx_bf, zpe_bf, w1p, w2p, ct_g, tgt_emb,
                                             sub_nodes, sub_counts, target_nodes, b2, out);
}

// Round 8
// 242.008 us; speedup vs baseline: 1.9302x; 1.0285x over previous
//
#include <hip/hip_runtime.h>
#include <hip/hip_bf16.h>

#define NN   100000
#define DD   128
#define ZZ   128
#define TT   1024
#define KK   256
#define HIDD 512

typedef __attribute__((ext_vector_type(8))) short  short8;   // 8 bf16 (MFMA A/B frag)
typedef __attribute__((ext_vector_type(4))) float  f32x4;    // MFMA C/D frag

__device__ inline unsigned short f2bf(float f) {  // RTNE fp32 -> bf16
    union { float f; unsigned int u; } x; x.f = f;
    unsigned int r = x.u + 0x7fffu + ((x.u >> 16) & 1u);
    return (unsigned short)(r >> 16);
}
__device__ inline void load_lds16(const void* g, void* l) {
    __builtin_amdgcn_global_load_lds((const __attribute__((address_space(1))) unsigned int*)g,
                                     (__attribute__((address_space(3))) unsigned int*)l, 16, 0, 0);
}

// ---------------- Kernel 1: ctx cast to bf16 (zpe table eliminated: rank-4 trick) ----------------
__global__ __launch_bounds__(256) void prep_tables(
    const float* __restrict__ ctx, unsigned short* __restrict__ ctx_bf) {
    int g = blockIdx.x * 256 + threadIdx.x;      // one thread per 8 elements
    if (g >= NN * 16) return;
    float4 c0 = *(const float4*)(ctx + (size_t)g * 8);
    float4 c1 = *(const float4*)(ctx + (size_t)g * 8 + 4);
    short8 sc;
    sc[0] = (short)f2bf(c0.x); sc[1] = (short)f2bf(c0.y);
    sc[2] = (short)f2bf(c0.z); sc[3] = (short)f2bf(c0.w);
    sc[4] = (short)f2bf(c1.x); sc[5] = (short)f2bf(c1.y);
    sc[6] = (short)f2bf(c1.z); sc[7] = (short)f2bf(c1.w);
    *(short8*)(ctx_bf + (size_t)g * 8) = sc;
}

// ---------------- Kernel 2: pack W1a/W2 frags + W1b'=Wpe@W1b compact + ct = b1+z@W1b+z_tgt@W1c ----
// Frag tile (16 out x 32 k): lane l elem e -> k_local = (l>>4)*8 + e, out = l&15.
// Blocks 0..255: W1a (k<128). 256..511: W2. 512..639: ct (8 targets each). 640..647: W1b'.
__global__ __launch_bounds__(256) void pack_ct(
    const float* __restrict__ W1, const float* __restrict__ W2,
    const float* __restrict__ pe, const float* __restrict__ z, const float* __restrict__ wpe,
    const int* __restrict__ target_nodes, const float* __restrict__ b1,
    unsigned short* __restrict__ w1p, unsigned short* __restrict__ w2p,
    unsigned short* __restrict__ w1pe, float* __restrict__ ct_g) {
    __shared__ float zp[8][128];
    int tid = threadIdx.x;
    int b = blockIdx.x;
    if (b < 256) {                                   // W1a rows 0..127 (ctx part)
        int g = b * 256 + tid;
        int e = g & 7, l = (g >> 3) & 63, tile = g >> 9;   // tile 0..127
        int ntg = tile & 7, rem = tile >> 3;               // rem = hc*4 + kc
        int kc = rem & 3, hc = rem >> 2;
        int k = kc * 32 + (l >> 4) * 8 + e;                // 0..127
        int n = hc * 128 + ntg * 16 + (l & 15);
        w1p[g] = f2bf(W1[(size_t)k * HIDD + n]);
        return;
    }
    if (b < 512) {                                   // W2
        int q = (b - 256) * 256 + tid;
        int e = q & 7, l = (q >> 3) & 63, tile = q >> 9;
        int ntg = tile & 7, kcg = tile >> 3;
        int k = kcg * 32 + (l >> 4) * 8 + e;
        int n = ntg * 16 + (l & 15);
        w2p[q] = f2bf(W2[(size_t)k * DD + n]);
        return;
    }
    if (b < 640) {                                   // ct for 8 targets
        int bb = b - 512;
#pragma unroll
        for (int q = 0; q < 4; ++q) {
            int idx = q * 256 + tid;                 // 0..1023
            int t8 = idx >> 7, zz = idx & 127;
            int tgt = target_nodes[bb * 8 + t8];
            zp[t8][zz] = z[zz] + pe[tgt * 4 + 0] * wpe[zz] + pe[tgt * 4 + 1] * wpe[128 + zz]
                               + pe[tgt * 4 + 2] * wpe[256 + zz] + pe[tgt * 4 + 3] * wpe[384 + zz];
        }
        __syncthreads();
        int j0 = tid, j1 = tid + 256;
        float a0[8], a1[8];
        float zb0 = b1[j0], zb1v = b1[j1];           // accumulate b1 + z@W1b here
#pragma unroll
        for (int t8 = 0; t8 < 8; ++t8) { a0[t8] = 0.f; a1[t8] = 0.f; }
#pragma unroll 8
        for (int zz = 0; zz < 128; ++zz) {
            float zv  = z[zz];
            float wb0 = W1[(size_t)(128 + zz) * HIDD + j0];
            float wb1 = W1[(size_t)(128 + zz) * HIDD + j1];
            float wc0 = W1[(size_t)(256 + zz) * HIDD + j0];
            float wc1 = W1[(size_t)(256 + zz) * HIDD + j1];
            zb0 += zv * wb0; zb1v += zv * wb1;
#pragma unroll
            for (int t8 = 0; t8 < 8; ++t8) { a0[t8] += zp[t8][zz] * wc0; a1[t8] += zp[t8][zz] * wc1; }
        }
#pragma unroll
        for (int t8 = 0; t8 < 8; ++t8) {
            ct_g[(size_t)(bb * 8 + t8) * HIDD + j0] = a0[t8] + zb0;
            ct_g[(size_t)(bb * 8 + t8) * HIDD + j1] = a1[t8] + zb1v;
        }
        return;
    }
    // W1b'[j][col] = sum_k wpe[j][k] * W1[128+k][col], compact layout [hc][ntg][lo][e=j]
    int idx = b - 640;                               // 0..7
    int j = idx >> 1, half = idx & 1;
    int col = half * 256 + tid;                      // 0..511
    float acc = 0.f;
#pragma unroll 8
    for (int k2 = 0; k2 < 128; ++k2) acc += wpe[j * 128 + k2] * W1[(size_t)(128 + k2) * HIDD + col];
    int hc = col >> 7, ntg = (col >> 4) & 7, lo2 = col & 15;
    w1pe[(((hc * 8 + ntg) * 16) + lo2) * 4 + j] = f2bf(acc);
}

// ---------------- Kernel 3: fused gather + MLP + masked-MSE ----------------
// Block = (target t, 64-row K-tile), 8 waves / 512 threads. Wave w: wm=w&1 (row half),
// wn=w>>1 (16-col tile pair). GEMM1 K=128(ctx) + rank-4 pe tile (zero-padded K=32 MFMA,
// compact 8B/lane weights on hi==0 lanes). GEMM1 swapped -> b64 hT writes conflict-free
// with ^((row&7)<<4); GEMM2 b128 reads use the same swizzle.
__global__ __launch_bounds__(512) void mp_jepa_main(
    const unsigned short* __restrict__ ctx_bf,
    const unsigned short* __restrict__ w1p,
    const unsigned short* __restrict__ w2p,
    const unsigned short* __restrict__ w1pe,
    const float* __restrict__ ct_g,
    const float* __restrict__ target_embedding,
    const float* __restrict__ pe,
    const int* __restrict__ sub_nodes,
    const int* __restrict__ sub_counts,
    const int* __restrict__ target_nodes,
    const float* __restrict__ b2,
    float* __restrict__ out) {
    const int bid = blockIdx.x;
    const int kt = bid >> 10, t = bid & 1023;         // kt-major: uniform load mix per CU
    const int k0 = kt * 64;
    int cnt = sub_counts[t]; if (cnt < 1) cnt = 1;
    if (k0 >= cnt) return;           // uniform early-exit before any barrier
    const int tgt = target_nodes[t];

    __shared__ __align__(16) unsigned short ctxT[64 * 128];  // 16 KB, swizzled ^((row&7)<<4)
    __shared__ __align__(16) unsigned short hT[64 * 128];    // 16 KB, swizzled
    __shared__ __align__(16) unsigned short peT[64 * 4];     // 512 B (bf16 pe rows)
    __shared__ __align__(16) float cts[HIDD];
    __shared__ float tgte[DD];
    __shared__ float b2s[DD];
    __shared__ float red[8];

    const int tid = threadIdx.x;
    const int w = tid >> 6, l = tid & 63;
    const int wm = w & 1, wn = w >> 1;                // row half / col-tile pair
    const int lo = l & 15, hi = l >> 4;
    const int base = t * KK + k0;

    // Async gather of ctx rows: linear LDS dest, inverse-swizzled global source.
    {
        const char* cc = (const char*)ctx_bf;
#pragma unroll
        for (int it = 0; it < 2; ++it) {
            int rgrp = it * 32 + (w << 2);        // wave-uniform row-group base (4 rows)
            int row  = rgrp + hi;
            int node = sub_nodes[base + row];
            int soff = (lo << 4) ^ ((row & 7) << 4);
            load_lds16(cc + (size_t)node * 256 + soff, (char*)ctxT + rgrp * 256);
        }
    }
    // pe rows (fp32 -> bf16), params; overlaps the in-flight gather
    if (tid < 64) {
        int node = sub_nodes[base + tid];
        float4 pv = *(const float4*)(pe + (size_t)node * 4);
        peT[tid * 4 + 0] = f2bf(pv.x); peT[tid * 4 + 1] = f2bf(pv.y);
        peT[tid * 4 + 2] = f2bf(pv.z); peT[tid * 4 + 3] = f2bf(pv.w);
    }
    if (tid < 128) {
        tgte[tid] = target_embedding[(size_t)tgt * 128 + tid];
        b2s[tid]  = b2[tid];
    }
    cts[tid] = ct_g[(size_t)t * HIDD + tid];
    __syncthreads();

    const short8* w1v = (const short8*)w1p;
    const short8* w2v = (const short8*)w2p;

    f32x4 accP[2][2];                                 // [rg][nt]: rows wm*32+rg*16, cols (wn*2+nt)*16
#pragma unroll
    for (int rg = 0; rg < 2; ++rg)
#pragma unroll
        for (int nt = 0; nt < 2; ++nt) accP[rg][nt] = (f32x4){0.f, 0.f, 0.f, 0.f};

    for (int hc = 0; hc < 4; ++hc) {
        // ---- GEMM1 (swapped): acc1[rg][nt]: hcols (wn*2+nt)*16 + hi*4 + r, agg-rows wm*32+rg*16+lo
        f32x4 acc1[2][2];
#pragma unroll
        for (int nt = 0; nt < 2; ++nt) {
            f32x4 cv = *(const f32x4*)&cts[(hc << 7) + (((wn << 1) + nt) << 4) + (hi << 2)];
            acc1[0][nt] = cv;
            acc1[1][nt] = cv;
        }
#pragma unroll
        for (int kc = 0; kc < 4; ++kc) {              // ctx part: K=128
            short8 bf0 = w1v[((((hc << 2) + kc) << 3) + (wn << 1) + 0) * 64 + l];
            short8 bf1 = w1v[((((hc << 2) + kc) << 3) + (wn << 1) + 1) * 64 + l];
            int cb = (kc << 6) + (hi << 4);
            short8 a[2];
#pragma unroll
            for (int rg = 0; rg < 2; ++rg) {
                int row = (wm << 5) + (rg << 4) + lo;
                a[rg] = *(const short8*)(ctxT + ((row * 256 + (cb ^ ((row & 7) << 4))) >> 1));
            }
#pragma unroll
            for (int rg = 0; rg < 2; ++rg) {
                acc1[rg][0] = __builtin_amdgcn_mfma_f32_16x16x32_bf16(bf0, a[rg], acc1[rg][0], 0, 0, 0);
                acc1[rg][1] = __builtin_amdgcn_mfma_f32_16x16x32_bf16(bf1, a[rg], acc1[rg][1], 0, 0, 0);
            }
        }
        // ---- pe rank-4 tile (zero-padded K=32): weights on hi==0 lanes only
        {
            short8 wf[2];
#pragma unroll
            for (int nt = 0; nt < 2; ++nt) {
                unsigned long long wv = 0ull;
                if (hi == 0)
                    wv = *(const unsigned long long*)(w1pe + (((((hc << 3) + (wn << 1) + nt) << 4) + lo) << 2));
                wf[nt] = (short8){(short)wv, (short)(wv >> 16), (short)(wv >> 32), (short)(wv >> 48),
                                  0, 0, 0, 0};
            }
#pragma unroll
            for (int rg = 0; rg < 2; ++rg) {
                int row = (wm << 5) + (rg << 4) + lo;
                unsigned long long pv = 0ull;
                if (hi == 0) pv = *(const unsigned long long*)(peT + (row << 2));
                short8 ap = (short8){(short)pv, (short)(pv >> 16), (short)(pv >> 32), (short)(pv >> 48),
                                     0, 0, 0, 0};
                acc1[rg][0] = __builtin_amdgcn_mfma_f32_16x16x32_bf16(wf[0], ap, acc1[rg][0], 0, 0, 0);
                acc1[rg][1] = __builtin_amdgcn_mfma_f32_16x16x32_bf16(wf[1], ap, acc1[rg][1], 0, 0, 0);
            }
        }

        __syncthreads();  // prior GEMM2 finished reading hT
        // relu -> bf16 -> hT: each lane writes 4 consecutive h-cols of one agg-row (b64)
#pragma unroll
        for (int nt = 0; nt < 2; ++nt) {
            int cbase = (((wn << 1) + nt) << 5) + (hi << 3);   // byte offset of 4 h-cols
#pragma unroll
            for (int rg = 0; rg < 2; ++rg) {
                int row = (wm << 5) + (rg << 4) + lo;
                f32x4 v = acc1[rg][nt];
                float v0 = v[0] > 0.f ? v[0] : 0.f;
                float v1 = v[1] > 0.f ? v[1] : 0.f;
                float v2 = v[2] > 0.f ? v[2] : 0.f;
                float v3 = v[3] > 0.f ? v[3] : 0.f;
                uint2 p;
                p.x = (unsigned int)f2bf(v0) | ((unsigned int)f2bf(v1) << 16);
                p.y = (unsigned int)f2bf(v2) | ((unsigned int)f2bf(v3) << 16);
                *(uint2*)((char*)hT + row * 256 + (cbase ^ ((row & 7) << 4))) = p;
            }
        }
        __syncthreads();

        // ---- GEMM2 partial: pred += relu_h[64,128] @ W2[hc*128.., 128]
#pragma unroll
        for (int kc2 = 0; kc2 < 4; ++kc2) {
            short8 bg0 = w2v[((((hc << 2) + kc2) << 3) + (wn << 1) + 0) * 64 + l];
            short8 bg1 = w2v[((((hc << 2) + kc2) << 3) + (wn << 1) + 1) * 64 + l];
            int cb = (kc2 << 6) + (hi << 4);
#pragma unroll
            for (int rg = 0; rg < 2; ++rg) {
                int row = (wm << 5) + (rg << 4) + lo;
                short8 a = *(const short8*)(hT + ((row * 256 + (cb ^ ((row & 7) << 4))) >> 1));
                accP[rg][0] = __builtin_amdgcn_mfma_f32_16x16x32_bf16(a, bg0, accP[rg][0], 0, 0, 0);
                accP[rg][1] = __builtin_amdgcn_mfma_f32_16x16x32_bf16(a, bg1, accP[rg][1], 0, 0, 0);
            }
        }
    }

    // ---- masked squared error + reduction
    float s = 0.f;
#pragma unroll
    for (int nt = 0; nt < 2; ++nt) {
        int col = (((wn << 1) + nt) << 4) + lo;
        float bb = b2s[col] - tgte[col];
#pragma unroll
        for (int rg = 0; rg < 2; ++rg) {
#pragma unroll
            for (int r = 0; r < 4; ++r) {
                int row = (wm << 5) + (rg << 4) + (hi << 2) + r;  // C/D: col=lane&15, row=(lane>>4)*4+r
                float d = accP[rg][nt][r] + bb;
                if (k0 + row < cnt) s += d * d;
            }
        }
    }
#pragma unroll
    for (int off = 32; off > 0; off >>= 1) s += __shfl_xor(s, off, 64);
    if (l == 0) red[w] = s;
    __syncthreads();
    if (tid == 0) {
        float tot = (red[0] + red[1] + red[2] + red[3] + red[4] + red[5] + red[6] + red[7])
                    / ((float)cnt * 128.0f);
        atomicAdd(out, tot);
    }
}

extern "C" void kernel_launch(void* const* d_in, const int* in_sizes, int n_in,
                              void* d_out, int out_size, void* d_ws, size_t ws_size,
                              hipStream_t stream) {
    const float* pe           = (const float*)d_in[0];
    const float* ctx          = (const float*)d_in[1];
    const float* tgt_emb      = (const float*)d_in[2];
    const int*   sub_nodes    = (const int*)d_in[3];
    const int*   sub_counts   = (const int*)d_in[4];
    const int*   target_nodes = (const int*)d_in[5];
    const float* z            = (const float*)d_in[6];
    const float* wpe          = (const float*)d_in[7];
    const float* W1           = (const float*)d_in[8];
    const float* b1           = (const float*)d_in[9];
    const float* W2           = (const float*)d_in[10];
    const float* b2           = (const float*)d_in[11];
    float* out = (float*)d_out;

    char* ws = (char*)d_ws;
    unsigned short* ctx_bf = (unsigned short*)ws;                          // 25.6 MB
    unsigned short* w1p    = (unsigned short*)(ws + 25600000);             // 128 KB
    unsigned short* w2p    = (unsigned short*)(ws + 25600000 + 131072);    // 128 KB
    unsigned short* w1pe   = (unsigned short*)(ws + 25600000 + 262144);    // 4 KB
    float*          ct_g   = (float*)(ws + 25600000 + 262144 + 4096);      // 2 MB

    hipMemsetAsync(d_out, 0, sizeof(float), stream);
    prep_tables<<<(NN * 16 + 255) / 256, 256, 0, stream>>>(ctx, ctx_bf);
    pack_ct<<<648, 256, 0, stream>>>(W1, W2, pe, z, wpe, target_nodes, b1, w1p, w2p, w1pe, ct_g);
    mp_jepa_main<<<TT * 4, 512, 0, stream>>>(ctx_bf, w1p, w2p, w1pe, ct_g, tgt_emb, pe,
                                             sub_nodes, sub_counts, target_nodes, b2, out);
}